// Round 1
// baseline (199.551 us; speedup 1.0000x reference)
//
#include <hip/hip_runtime.h>

#define IMG 224
#define HW (IMG * IMG)
#define TILE 32

__global__ __launch_bounds__(256) void vm_kernel(
    const float* __restrict__ im1, const float* __restrict__ im2,
    const float* __restrict__ C, const float* __restrict__ M1,
    const float* __restrict__ M2, float* __restrict__ out)
{
    // +1 padding -> conflict-free in both access orders
    __shared__ float sC0[TILE][TILE + 1];
    __shared__ float sC1[TILE][TILE + 1];
    __shared__ float sM1[TILE][TILE + 1];
    __shared__ float sM2[TILE][TILE + 1];
    __shared__ float sO[3][TILE][TILE + 1];

    const int n    = blockIdx.y;
    const int tile = blockIdx.x;          // 0..48
    const int x0   = (tile / 7) * TILE;   // slow output dim (p / 224)
    const int y0   = (tile % 7) * TILE;   // fast output dim (p % 224)
    const int t    = threadIdx.x;

    const float* Cn  = C  + (size_t)n * 2 * HW;
    const float* M1n = M1 + (size_t)n * HW;
    const float* M2n = M2 + (size_t)n * HW;

    // ---- phase 1: coalesced tile load of C0, C1, M1, M2 (output-layout order)
#pragma unroll
    for (int j = 0; j < 4; ++j) {
        int idx = t + 256 * j;            // 0..1023
        int tx  = idx >> 5;               // x offset in tile
        int ty  = idx & 31;               // y offset (fast in memory)
        int p   = (x0 + tx) * IMG + (y0 + ty);
        sC0[tx][ty] = Cn[p];
        sC1[tx][ty] = Cn[HW + p];
        sM1[tx][ty] = M1n[p];
        sM2[tx][ty] = M2n[p];
    }
    __syncthreads();

    const float* i1n = im1 + (size_t)n * 3 * HW;
    const float* i2n = im2 + (size_t)n * 3 * HW;

    // ---- phase 2: compute in TRANSPOSED order (x fast) so gathers coalesce
#pragma unroll
    for (int j = 0; j < 4; ++j) {
        int idx = t + 256 * j;
        int xl  = idx & 31;               // x fast across lanes
        int yl  = idx >> 5;
        float c0 = sC0[xl][yl];
        float c1 = sC1[xl][yl];
        float m1 = sM1[xl][yl];
        float m2 = sM2[xl][yl];
        float xf = (float)(x0 + xl);
        float yf = (float)(y0 + yl);

        // --- direction +C on im1
        float pxa = xf + c0, pya = yf + c1;
        float fxa = floorf(pxa), cxa = ceilf(pxa);
        float fya = floorf(pya), cya = ceilf(pya);
        float wfxa = 1.0f - (pxa - fxa), wcxa = 1.0f - (cxa - pxa);
        float wfya = 1.0f - (pya - fya), wcya = 1.0f - (cya - pya);
        int ia00 = min(max((int)fxa + IMG * (int)fya, 0), HW - 1);
        int ia10 = min(max((int)cxa + IMG * (int)fya, 0), HW - 1);
        int ia01 = min(max((int)fxa + IMG * (int)cya, 0), HW - 1);
        int ia11 = min(max((int)cxa + IMG * (int)cya, 0), HW - 1);
        float wa00 = wfxa * wfya, wa10 = wcxa * wfya;
        float wa01 = wfxa * wcya, wa11 = wcxa * wcya;

        // --- direction -C on im2
        float pxb = xf - c0, pyb = yf - c1;
        float fxb = floorf(pxb), cxb = ceilf(pxb);
        float fyb = floorf(pyb), cyb = ceilf(pyb);
        float wfxb = 1.0f - (pxb - fxb), wcxb = 1.0f - (cxb - pxb);
        float wfyb = 1.0f - (pyb - fyb), wcyb = 1.0f - (cyb - pyb);
        int ib00 = min(max((int)fxb + IMG * (int)fyb, 0), HW - 1);
        int ib10 = min(max((int)cxb + IMG * (int)fyb, 0), HW - 1);
        int ib01 = min(max((int)fxb + IMG * (int)cyb, 0), HW - 1);
        int ib11 = min(max((int)cxb + IMG * (int)cyb, 0), HW - 1);
        float wb00 = wfxb * wfyb, wb10 = wcxb * wfyb;
        float wb01 = wfxb * wcyb, wb11 = wcxb * wcyb;

#pragma unroll
        for (int ch = 0; ch < 3; ++ch) {
            const float* pa = i1n + ch * HW;
            const float* pb = i2n + ch * HW;
            float a = wa00 * pa[ia00] + wa10 * pa[ia10]
                    + wa01 * pa[ia01] + wa11 * pa[ia11];
            float b = wb00 * pb[ib00] + wb10 * pb[ib10]
                    + wb01 * pb[ib01] + wb11 * pb[ib11];
            sO[ch][xl][yl] = a * m1 + b * m2;
        }
    }
    __syncthreads();

    // ---- phase 3: coalesced store in output-layout order
    float* on = out + (size_t)n * 3 * HW;
#pragma unroll
    for (int j = 0; j < 4; ++j) {
        int idx = t + 256 * j;
        int tx  = idx >> 5;
        int ty  = idx & 31;
        int p   = (x0 + tx) * IMG + (y0 + ty);
#pragma unroll
        for (int ch = 0; ch < 3; ++ch) {
            on[ch * HW + p] = sO[ch][tx][ty];
        }
    }
}

extern "C" void kernel_launch(void* const* d_in, const int* in_sizes, int n_in,
                              void* d_out, int out_size, void* d_ws, size_t ws_size,
                              hipStream_t stream) {
    const float* im1 = (const float*)d_in[0];
    const float* im2 = (const float*)d_in[1];
    const float* C   = (const float*)d_in[2];
    const float* M1  = (const float*)d_in[3];
    const float* M2  = (const float*)d_in[4];
    float* out = (float*)d_out;
    dim3 grid(49, 64);  // 7x7 tiles of 32x32, 64 batch
    vm_kernel<<<grid, 256, 0, stream>>>(im1, im2, C, M1, M2, out);
}